// Round 1
// baseline (110.103 us; speedup 1.0000x reference)
//
#include <hip/hip_runtime.h>
#include <cstdint>
#include <cstddef>

typedef float  f32x4  __attribute__((ext_vector_type(4)));
typedef short  bf16x8 __attribute__((ext_vector_type(8)));
typedef unsigned short u16x8 __attribute__((ext_vector_type(8)));

#define L_SEQ   8192
#define D_DIM   1024
#define N_COL   2048     // Bu columns: interleaved (re,im) per complex channel
#define N_PAIR  512      // channel pairs (2 complex channels per thread)
#define CHUNK_T 64       // time steps per chunk
#define N_CHUNK 128      // L_SEQ / CHUNK_T

// ---------- helpers ----------
__device__ __forceinline__ unsigned short f2bf(float f) {
  unsigned int b = __float_as_uint(f);
  b += 0x7FFFu + ((b >> 16) & 1u);      // RNE
  return (unsigned short)(b >> 16);
}

__device__ __forceinline__ void gload_lds16(const void* g, void* lds) {
  __builtin_amdgcn_global_load_lds(
      (const __attribute__((address_space(1))) void*)g,
      (__attribute__((address_space(3))) void*)lds, 16, 0, 0);
}

// ---------- K1a: lambda per complex channel ----------
__global__ void k_lam(const float* __restrict__ theta, const float* __restrict__ nu,
                      float2* __restrict__ lam) {
  int k = blockIdx.x * blockDim.x + threadIdx.x;
  if (k >= D_DIM) return;
  float mod = expf(-expf(nu[k]));
  float ang = expf(theta[k]);
  lam[k] = make_float2(mod * cosf(ang), mod * sinf(ang));
}

// ---------- K1b: inputs f32 -> bf16 ----------
__global__ void k_cvt_in(const float* __restrict__ in, unsigned short* __restrict__ A) {
  int i = blockIdx.x * blockDim.x + threadIdx.x;   // one thread per 8 elements
  const float4* p = (const float4*)in;
  float4 a = p[2 * i], b = p[2 * i + 1];
  u16x8 o;
  o[0] = f2bf(a.x); o[1] = f2bf(a.y); o[2] = f2bf(a.z); o[3] = f2bf(a.w);
  o[4] = f2bf(b.x); o[5] = f2bf(b.y); o[6] = f2bf(b.z); o[7] = f2bf(b.w);
  *(u16x8*)(A + (size_t)i * 8) = o;
}

// ---------- K1c: W[2048][1024] bf16, row 2k = gamma_k*B_re[k,:], row 2k+1 = gamma_k*B_im[k,:]
__global__ void k_w(const float* __restrict__ Bre, const float* __restrict__ Bim,
                    const float* __restrict__ gamma_log, unsigned short* __restrict__ W) {
  int t = blockIdx.x * blockDim.x + threadIdx.x;   // 0..262143 (one per 8 elems)
  int row = t >> 7;
  int seg = t & 127;
  int k = row >> 1;
  const float* src = (row & 1) ? Bim : Bre;
  float g = expf(gamma_log[k]);
  const float4* p = (const float4*)(src + (size_t)k * D_DIM + seg * 8);
  float4 a = p[0], b = p[1];
  u16x8 o;
  o[0] = f2bf(a.x * g); o[1] = f2bf(a.y * g); o[2] = f2bf(a.z * g); o[3] = f2bf(a.w * g);
  o[4] = f2bf(b.x * g); o[5] = f2bf(b.y * g); o[6] = f2bf(b.z * g); o[7] = f2bf(b.w * g);
  *(u16x8*)(W + (size_t)row * D_DIM + seg * 8) = o;
}

// ---------- K2: GEMM  Bu[8192][2048] = A[8192][1024] * W[2048][1024]^T  (bf16 MFMA)
__global__ __launch_bounds__(256) void k_gemm(const unsigned short* __restrict__ A,
                                              const unsigned short* __restrict__ W,
                                              float* __restrict__ Bu) {
  __shared__ unsigned short At[128 * 64];   // [row][64 k], swizzled 16B chunks
  __shared__ unsigned short Bt[128 * 64];

  const int bid = blockIdx.x;
  const int mt = bid & 63;        // 64 m-tiles
  const int nt = bid >> 6;        // 16 n-tiles
  const int m0 = mt * 128, n0 = nt * 128;
  const int tid = threadIdx.x;
  const int l = tid & 63, w = tid >> 6;
  const int wr = w >> 1, wc = w & 1;         // 2x2 wave grid, 64x64 per wave
  const int lrow = l >> 3;                    // 0..7  (row within 8-row issue)
  const int cs = l & 7;                       // stored 16B chunk slot
  const int cA = cs ^ lrow;                   // logical chunk to fetch (involution)

  f32x4 acc[4][4];
#pragma unroll
  for (int m = 0; m < 4; ++m)
#pragma unroll
    for (int n = 0; n < 4; ++n) acc[m][n] = (f32x4){0.f, 0.f, 0.f, 0.f};

#define STAGE(KT)                                                                 \
  do {                                                                            \
    _Pragma("unroll")                                                             \
    for (int i = 0; i < 4; ++i) {                                                 \
      int r = w * 32 + i * 8 + lrow;                                              \
      const unsigned short* ga = A + (size_t)(m0 + r) * 1024 + (KT) * 64 + cA * 8;\
      gload_lds16(ga, At + (size_t)(w * 32 + i * 8) * 64);                        \
      const unsigned short* gb = W + (size_t)(n0 + r) * 1024 + (KT) * 64 + cA * 8;\
      gload_lds16(gb, Bt + (size_t)(w * 32 + i * 8) * 64);                        \
    }                                                                             \
  } while (0)

  STAGE(0);

  for (int kt = 0; kt < 16; ++kt) {
    __syncthreads();   // staged tile visible (barrier drains vmcnt)
    bf16x8 af[2][4], bfr[2][4];
#pragma unroll
    for (int ks = 0; ks < 2; ++ks) {
      const int c = ks * 4 + (l >> 4);
#pragma unroll
      for (int m = 0; m < 4; ++m) {
        int rowa = wr * 64 + m * 16 + (l & 15);
        af[ks][m] = *(const bf16x8*)((const char*)At + rowa * 128 + ((c ^ (rowa & 7)) << 4));
        int rowb = wc * 64 + m * 16 + (l & 15);
        bfr[ks][m] = *(const bf16x8*)((const char*)Bt + rowb * 128 + ((c ^ (rowb & 7)) << 4));
      }
    }
#pragma unroll
    for (int ks = 0; ks < 2; ++ks)
#pragma unroll
      for (int m = 0; m < 4; ++m)
#pragma unroll
        for (int n = 0; n < 4; ++n)
          acc[m][n] = __builtin_amdgcn_mfma_f32_16x16x32_bf16(af[ks][m], bfr[ks][n],
                                                              acc[m][n], 0, 0, 0);
    __syncthreads();   // everyone done reading before overwrite
    if (kt + 1 < 16) STAGE(kt + 1);
  }
#undef STAGE

  // epilogue: C/D layout col = l&15, row = (l>>4)*4 + reg
#pragma unroll
  for (int m = 0; m < 4; ++m)
#pragma unroll
    for (int n = 0; n < 4; ++n) {
      int col = n0 + wc * 64 + n * 16 + (l & 15);
#pragma unroll
      for (int j = 0; j < 4; ++j) {
        int row = m0 + wr * 64 + m * 16 + (l >> 4) * 4 + j;
        Bu[(size_t)row * N_COL + col] = acc[m][n][j];
      }
    }
}

// complex fma: h = lam*h + b  (two channels per thread)
__device__ __forceinline__ void cfma2(const float4& lm, float2& h0, float2& h1,
                                      const float4& v) {
  float nr0 = fmaf(lm.x, h0.x, fmaf(-lm.y, h0.y, v.x));
  float ni0 = fmaf(lm.x, h0.y, fmaf(lm.y, h0.x, v.y));
  float nr1 = fmaf(lm.z, h1.x, fmaf(-lm.w, h1.y, v.z));
  float ni1 = fmaf(lm.z, h1.y, fmaf(lm.w, h1.x, v.w));
  h0.x = nr0; h0.y = ni0; h1.x = nr1; h1.y = ni1;
}

// ---------- K3: per-chunk local scan finals ----------
__global__ __launch_bounds__(256) void k_scan1(const float4* __restrict__ Bu4,
                                               const float4* __restrict__ lam4,
                                               float4* __restrict__ agg4) {
  int t = blockIdx.x * 256 + threadIdx.x;      // 0..65535
  int c = t >> 9, j = t & 511;
  float4 lm = lam4[j];
  float2 h0 = {0.f, 0.f}, h1 = {0.f, 0.f};
  const float4* p = Bu4 + (size_t)c * CHUNK_T * N_PAIR + j;
#pragma unroll 8
  for (int s = 0; s < CHUNK_T; ++s) {
    float4 v = *p; p += N_PAIR;
    cfma2(lm, h0, h1, v);
  }
  agg4[(size_t)c * N_PAIR + j] = make_float4(h0.x, h0.y, h1.x, h1.y);
}

// ---------- K4: scan of chunk aggregates (exclusive carries) ----------
__global__ __launch_bounds__(256) void k_scan2(const float4* __restrict__ agg4,
                                               const float4* __restrict__ lam4,
                                               float4* __restrict__ carry4) {
  int j = blockIdx.x * 256 + threadIdx.x;      // 0..511
  if (j >= N_PAIR) return;
  float4 lm = lam4[j];
  float2 l0 = {lm.x, lm.y}, l1 = {lm.z, lm.w};
#pragma unroll
  for (int i = 0; i < 6; ++i) {                // lambda^64 (CHUNK_T = 2^6)
    l0 = make_float2(l0.x * l0.x - l0.y * l0.y, 2.f * l0.x * l0.y);
    l1 = make_float2(l1.x * l1.x - l1.y * l1.y, 2.f * l1.x * l1.y);
  }
  float4 lT = make_float4(l0.x, l0.y, l1.x, l1.y);
  float2 s0 = {0.f, 0.f}, s1 = {0.f, 0.f};
  for (int c = 0; c < N_CHUNK; ++c) {
    carry4[(size_t)c * N_PAIR + j] = make_float4(s0.x, s0.y, s1.x, s1.y);
    float4 a = agg4[(size_t)c * N_PAIR + j];
    cfma2(lT, s0, s1, a);
  }
}

// ---------- K5: final rescan + output ----------
__global__ __launch_bounds__(256) void k_scan3(const float4* __restrict__ Bu4,
                                               const float4* __restrict__ lam4,
                                               const float4* __restrict__ carry4,
                                               const float2* __restrict__ in2,
                                               float2* __restrict__ out2) {
  int t = blockIdx.x * 256 + threadIdx.x;      // 0..65535
  int c = t >> 9, j = t & 511;
  float4 lm = lam4[j];
  float4 cv = carry4[(size_t)c * N_PAIR + j];
  float2 h0 = {cv.x, cv.y}, h1 = {cv.z, cv.w};
  size_t base = (size_t)c * CHUNK_T * N_PAIR + j;
#pragma unroll 8
  for (int s = 0; s < CHUNK_T; ++s) {
    float4 v = Bu4[base + (size_t)s * N_PAIR];
    cfma2(lm, h0, h1, v);
    float2 iv = in2[base + (size_t)s * N_PAIR];
    out2[base + (size_t)s * N_PAIR] = make_float2(h0.x + iv.x, h1.x + iv.y);
  }
}

extern "C" void kernel_launch(void* const* d_in, const int* in_sizes, int n_in,
                              void* d_out, int out_size, void* d_ws, size_t ws_size,
                              hipStream_t stream) {
  (void)in_sizes; (void)n_in; (void)out_size; (void)ws_size;
  const float* inputs    = (const float*)d_in[0];
  const float* theta     = (const float*)d_in[1];
  const float* nu        = (const float*)d_in[2];
  const float* gamma_log = (const float*)d_in[3];
  const float* Bre       = (const float*)d_in[4];
  const float* Bim       = (const float*)d_in[5];

  char* ws = (char*)d_ws;
  float2*         lam  = (float2*)ws;                                  // 8 KB
  unsigned short* A    = (unsigned short*)(ws + (1 << 16));            // 16 MB
  unsigned short* W    = (unsigned short*)(ws + (1 << 16) + (16u << 20)); // 4 MB
  float*          Bu   = (float*)(ws + (1 << 16) + (20u << 20));       // 64 MB
  float4*         agg  = (float4*)(ws + (1 << 16) + (84u << 20));      // 1 MB
  float4*         carry= (float4*)(ws + (1 << 16) + (85u << 20));      // 1 MB

  k_lam<<<4, 256, 0, stream>>>(theta, nu, lam);
  k_cvt_in<<<(L_SEQ * D_DIM / 8) / 256, 256, 0, stream>>>(inputs, A);
  k_w<<<(N_COL * D_DIM / 8) / 256, 256, 0, stream>>>(Bre, Bim, gamma_log, W);
  k_gemm<<<64 * 16, 256, 0, stream>>>(A, W, Bu);
  k_scan1<<<(N_CHUNK * N_PAIR) / 256, 256, 0, stream>>>((const float4*)Bu,
                                                        (const float4*)lam, agg);
  k_scan2<<<2, 256, 0, stream>>>(agg, (const float4*)lam, carry);
  k_scan3<<<(N_CHUNK * N_PAIR) / 256, 256, 0, stream>>>((const float4*)Bu,
                                                        (const float4*)lam, carry,
                                                        (const float2*)inputs,
                                                        (float2*)d_out);
}

// Round 2
// 95.030 us; speedup vs baseline: 1.1586x; 1.1586x over previous
//
#include <hip/hip_runtime.h>
#include <cstdint>
#include <cstddef>

typedef float  f32x4  __attribute__((ext_vector_type(4)));
typedef short  bf16x8 __attribute__((ext_vector_type(8)));
typedef unsigned short u16x8 __attribute__((ext_vector_type(8)));

#define L_SEQ   8192
#define D_DIM   1024
#define N_COL   2048     // Bu columns: interleaved (re,im) per complex channel
#define N_PAIR  512      // float4 channel pairs (2 complex channels)
#define CHUNK_T 16       // time steps per chunk
#define N_CHUNK 512      // L_SEQ / CHUNK_T

// ---------- helpers ----------
__device__ __forceinline__ unsigned short f2bf(float f) {
  unsigned int b = __float_as_uint(f);
  b += 0x7FFFu + ((b >> 16) & 1u);      // RNE
  return (unsigned short)(b >> 16);
}

__device__ __forceinline__ void gload_lds16(const void* g, void* lds) {
  __builtin_amdgcn_global_load_lds(
      (const __attribute__((address_space(1))) void*)g,
      (__attribute__((address_space(3))) void*)lds, 16, 0, 0);
}

__device__ __forceinline__ float2 cmul(float2 a, float2 b) {
  return make_float2(a.x * b.x - a.y * b.y, a.x * b.y + a.y * b.x);
}
__device__ __forceinline__ float2 csqr(float2 a) {
  return make_float2(a.x * a.x - a.y * a.y, 2.f * a.x * a.y);
}

// complex fma on two channels: h = lam*h + v
__device__ __forceinline__ void cfma2(const float4& lm, float2& h0, float2& h1,
                                      const float4& v) {
  float nr0 = fmaf(lm.x, h0.x, fmaf(-lm.y, h0.y, v.x));
  float ni0 = fmaf(lm.x, h0.y, fmaf(lm.y, h0.x, v.y));
  float nr1 = fmaf(lm.z, h1.x, fmaf(-lm.w, h1.y, v.z));
  float ni1 = fmaf(lm.z, h1.y, fmaf(lm.w, h1.x, v.w));
  h0.x = nr0; h0.y = ni0; h1.x = nr1; h1.y = ni1;
}

// ---------- K1: fused prep (inputs->bf16, W build, lambda) ----------
// blocks [0,4096): cvt inputs; [4096,5120): W; [5120,5124): lambda
__global__ __launch_bounds__(256) void k_prep(
    const float* __restrict__ in, const float* __restrict__ Bre,
    const float* __restrict__ Bim, const float* __restrict__ gamma_log,
    const float* __restrict__ theta, const float* __restrict__ nu,
    unsigned short* __restrict__ A, unsigned short* __restrict__ W,
    float2* __restrict__ lam) {
  int b = blockIdx.x;
  if (b < 4096) {
    int i = b * 256 + threadIdx.x;               // one thread per 8 elems
    const float4* p = (const float4*)in;
    float4 a = p[2 * i], c = p[2 * i + 1];
    u16x8 o;
    o[0] = f2bf(a.x); o[1] = f2bf(a.y); o[2] = f2bf(a.z); o[3] = f2bf(a.w);
    o[4] = f2bf(c.x); o[5] = f2bf(c.y); o[6] = f2bf(c.z); o[7] = f2bf(c.w);
    *(u16x8*)(A + (size_t)i * 8) = o;
  } else if (b < 5120) {
    int t = (b - 4096) * 256 + threadIdx.x;      // 0..262143
    int row = t >> 7;
    int seg = t & 127;
    int k = row >> 1;
    const float* src = (row & 1) ? Bim : Bre;
    float g = expf(gamma_log[k]);
    const float4* p = (const float4*)(src + (size_t)k * D_DIM + seg * 8);
    float4 a = p[0], c = p[1];
    u16x8 o;
    o[0] = f2bf(a.x * g); o[1] = f2bf(a.y * g); o[2] = f2bf(a.z * g); o[3] = f2bf(a.w * g);
    o[4] = f2bf(c.x * g); o[5] = f2bf(c.y * g); o[6] = f2bf(c.z * g); o[7] = f2bf(c.w * g);
    *(u16x8*)(W + (size_t)row * D_DIM + seg * 8) = o;
  } else {
    int k = (b - 5120) * 256 + threadIdx.x;
    if (k < D_DIM) {
      float mod = expf(-expf(nu[k]));
      float ang = expf(theta[k]);
      lam[k] = make_float2(mod * cosf(ang), mod * sinf(ang));
    }
  }
}

// ---------- K2: GEMM  Bu[8192][2048] = A[8192][1024] * W[2048][1024]^T  (bf16 MFMA)
__global__ __launch_bounds__(256) void k_gemm(const unsigned short* __restrict__ A,
                                              const unsigned short* __restrict__ W,
                                              float* __restrict__ Bu) {
  __shared__ unsigned short At[128 * 64];   // [row][64 k], swizzled 16B chunks
  __shared__ unsigned short Bt[128 * 64];

  const int bid = blockIdx.x;
  const int mt = bid & 63;        // 64 m-tiles
  const int nt = bid >> 6;        // 16 n-tiles
  const int m0 = mt * 128, n0 = nt * 128;
  const int tid = threadIdx.x;
  const int l = tid & 63, w = tid >> 6;
  const int wr = w >> 1, wc = w & 1;         // 2x2 wave grid, 64x64 per wave
  const int lrow = l >> 3;                    // 0..7  (row within 8-row issue)
  const int cs = l & 7;                       // stored 16B chunk slot
  const int cA = cs ^ lrow;                   // logical chunk to fetch (involution)

  f32x4 acc[4][4];
#pragma unroll
  for (int m = 0; m < 4; ++m)
#pragma unroll
    for (int n = 0; n < 4; ++n) acc[m][n] = (f32x4){0.f, 0.f, 0.f, 0.f};

#define STAGE(KT)                                                                 \
  do {                                                                            \
    _Pragma("unroll")                                                             \
    for (int i = 0; i < 4; ++i) {                                                 \
      int r = w * 32 + i * 8 + lrow;                                              \
      const unsigned short* ga = A + (size_t)(m0 + r) * 1024 + (KT) * 64 + cA * 8;\
      gload_lds16(ga, At + (size_t)(w * 32 + i * 8) * 64);                        \
      const unsigned short* gb = W + (size_t)(n0 + r) * 1024 + (KT) * 64 + cA * 8;\
      gload_lds16(gb, Bt + (size_t)(w * 32 + i * 8) * 64);                        \
    }                                                                             \
  } while (0)

  STAGE(0);

  for (int kt = 0; kt < 16; ++kt) {
    __syncthreads();   // staged tile visible (barrier drains vmcnt)
    bf16x8 af[2][4], bfr[2][4];
#pragma unroll
    for (int ks = 0; ks < 2; ++ks) {
      const int c = ks * 4 + (l >> 4);
#pragma unroll
      for (int m = 0; m < 4; ++m) {
        int rowa = wr * 64 + m * 16 + (l & 15);
        af[ks][m] = *(const bf16x8*)((const char*)At + rowa * 128 + ((c ^ (rowa & 7)) << 4));
        int rowb = wc * 64 + m * 16 + (l & 15);
        bfr[ks][m] = *(const bf16x8*)((const char*)Bt + rowb * 128 + ((c ^ (rowb & 7)) << 4));
      }
    }
#pragma unroll
    for (int ks = 0; ks < 2; ++ks)
#pragma unroll
      for (int m = 0; m < 4; ++m)
#pragma unroll
        for (int n = 0; n < 4; ++n)
          acc[m][n] = __builtin_amdgcn_mfma_f32_16x16x32_bf16(af[ks][m], bfr[ks][n],
                                                              acc[m][n], 0, 0, 0);
    __syncthreads();   // everyone done reading before overwrite
    if (kt + 1 < 16) STAGE(kt + 1);
  }
#undef STAGE

  // epilogue: C/D layout col = l&15, row = (l>>4)*4 + reg
#pragma unroll
  for (int m = 0; m < 4; ++m)
#pragma unroll
    for (int n = 0; n < 4; ++n) {
      int col = n0 + wc * 64 + n * 16 + (l & 15);
#pragma unroll
      for (int j = 0; j < 4; ++j) {
        int row = m0 + wr * 64 + m * 16 + (l >> 4) * 4 + j;
        Bu[(size_t)row * N_COL + col] = acc[m][n][j];
      }
    }
}

// ---------- K3: per-chunk local scan finals (agg[c][j]) ----------
__global__ __launch_bounds__(256) void k_scan1(const float4* __restrict__ Bu4,
                                               const float4* __restrict__ lam4,
                                               float4* __restrict__ agg4) {
  int t = blockIdx.x * 256 + threadIdx.x;      // 0..262143
  int c = t >> 9, j = t & 511;
  float4 lm = lam4[j];
  float2 h0 = {0.f, 0.f}, h1 = {0.f, 0.f};
  const float4* p = Bu4 + (size_t)c * CHUNK_T * N_PAIR + j;
#pragma unroll
  for (int s = 0; s < CHUNK_T; ++s) {
    float4 v = p[(size_t)s * N_PAIR];
    cfma2(lm, h0, h1, v);
  }
  agg4[(size_t)c * N_PAIR + j] = make_float4(h0.x, h0.y, h1.x, h1.y);
}

// ---------- K4: wave-parallel scan of chunk aggregates -> exclusive carries ----------
// one wave per channel-pair j; lane owns 8 consecutive chunks
__global__ __launch_bounds__(256) void k_scan2(const float4* __restrict__ agg4,
                                               const float4* __restrict__ lam4,
                                               float4* __restrict__ carry4) {
  int wave = blockIdx.x * 4 + (threadIdx.x >> 6);   // 0..511 = pair j
  int lane = threadIdx.x & 63;
  int j = wave;
  float4 lm = lam4[j];
  float2 lT0 = {lm.x, lm.y}, lT1 = {lm.z, lm.w};
#pragma unroll
  for (int i = 0; i < 4; ++i) { lT0 = csqr(lT0); lT1 = csqr(lT1); }  // lambda^16

  // load this lane's 8 chunk aggregates, compute inclusive total T
  float4 a[8];
  float2 T0 = {0.f, 0.f}, T1 = {0.f, 0.f};
  float4 lTv = make_float4(lT0.x, lT0.y, lT1.x, lT1.y);
#pragma unroll
  for (int i = 0; i < 8; ++i) {
    a[i] = agg4[(size_t)(lane * 8 + i) * N_PAIR + j];
    cfma2(lTv, T0, T1, a[i]);
  }

  // Kogge-Stone inclusive scan over 64 lanes, multiplier M = lambda^128
  float2 M0 = lT0, M1 = lT1;
#pragma unroll
  for (int i = 0; i < 3; ++i) { M0 = csqr(M0); M1 = csqr(M1); }
  float2 S0 = T0, S1 = T1;
#pragma unroll
  for (int d = 1; d < 64; d <<= 1) {
    float2 u0, u1;
    u0.x = __shfl_up(S0.x, d); u0.y = __shfl_up(S0.y, d);
    u1.x = __shfl_up(S1.x, d); u1.y = __shfl_up(S1.y, d);
    if (lane >= d) {
      float2 m0 = cmul(M0, u0), m1 = cmul(M1, u1);
      S0.x += m0.x; S0.y += m0.y; S1.x += m1.x; S1.y += m1.y;
    }
    M0 = csqr(M0); M1 = csqr(M1);
  }
  // exclusive prefix for this lane's first chunk
  float2 P0, P1;
  P0.x = __shfl_up(S0.x, 1); P0.y = __shfl_up(S0.y, 1);
  P1.x = __shfl_up(S1.x, 1); P1.y = __shfl_up(S1.y, 1);
  if (lane == 0) { P0 = make_float2(0.f, 0.f); P1 = make_float2(0.f, 0.f); }

  // walk the 8 chunks writing exclusive carries
#pragma unroll
  for (int i = 0; i < 8; ++i) {
    carry4[(size_t)(lane * 8 + i) * N_PAIR + j] = make_float4(P0.x, P0.y, P1.x, P1.y);
    cfma2(lTv, P0, P1, a[i]);
  }
}

// ---------- K5: final rescan + output (2 pairs / thread, float4 in & out) ----------
__global__ __launch_bounds__(256) void k_scan3(const float4* __restrict__ Bu4,
                                               const float4* __restrict__ lam4,
                                               const float4* __restrict__ carry4,
                                               const float4* __restrict__ in4,
                                               float4* __restrict__ out4) {
  int t = blockIdx.x * 256 + threadIdx.x;      // 0..131071
  int c = t >> 8, q = t & 255;                 // chunk, quad (4 channels)
  float4 lm0 = lam4[2 * q], lm1 = lam4[2 * q + 1];
  float4 cv0 = carry4[(size_t)c * N_PAIR + 2 * q];
  float4 cv1 = carry4[(size_t)c * N_PAIR + 2 * q + 1];
  float2 h0 = {cv0.x, cv0.y}, h1 = {cv0.z, cv0.w};
  float2 h2 = {cv1.x, cv1.y}, h3 = {cv1.z, cv1.w};
#pragma unroll
  for (int s = 0; s < CHUNK_T; ++s) {
    size_t row = (size_t)c * CHUNK_T + s;
    float4 v0 = Bu4[row * N_PAIR + 2 * q];
    float4 v1 = Bu4[row * N_PAIR + 2 * q + 1];
    cfma2(lm0, h0, h1, v0);
    cfma2(lm1, h2, h3, v1);
    float4 iv = in4[row * 256 + q];
    out4[row * 256 + q] = make_float4(h0.x + iv.x, h1.x + iv.y,
                                      h2.x + iv.z, h3.x + iv.w);
  }
}

extern "C" void kernel_launch(void* const* d_in, const int* in_sizes, int n_in,
                              void* d_out, int out_size, void* d_ws, size_t ws_size,
                              hipStream_t stream) {
  (void)in_sizes; (void)n_in; (void)out_size; (void)ws_size;
  const float* inputs    = (const float*)d_in[0];
  const float* theta     = (const float*)d_in[1];
  const float* nu        = (const float*)d_in[2];
  const float* gamma_log = (const float*)d_in[3];
  const float* Bre       = (const float*)d_in[4];
  const float* Bim       = (const float*)d_in[5];

  char* ws = (char*)d_ws;
  float2*         lam   = (float2*)ws;                                     // 8 KB
  unsigned short* A     = (unsigned short*)(ws + (1 << 16));               // 16 MB
  unsigned short* W     = (unsigned short*)(ws + (1 << 16) + (16u << 20)); // 4 MB
  float*          Bu    = (float*)(ws + (1 << 16) + (20u << 20));          // 64 MB
  float4*         agg   = (float4*)(ws + (1 << 16) + (84u << 20));         // 4 MB
  float4*         carry = (float4*)(ws + (1 << 16) + (88u << 20));         // 4 MB

  k_prep<<<5124, 256, 0, stream>>>(inputs, Bre, Bim, gamma_log, theta, nu, A, W, lam);
  k_gemm<<<64 * 16, 256, 0, stream>>>(A, W, Bu);
  k_scan1<<<(N_CHUNK * N_PAIR) / 256, 256, 0, stream>>>((const float4*)Bu,
                                                        (const float4*)lam, agg);
  k_scan2<<<N_PAIR / 4, 256, 0, stream>>>(agg, (const float4*)lam, carry);
  k_scan3<<<(N_CHUNK * 256) / 256, 256, 0, stream>>>((const float4*)Bu,
                                                     (const float4*)lam, carry,
                                                     (const float4*)inputs,
                                                     (float4*)d_out);
}

// Round 3
// 86.820 us; speedup vs baseline: 1.2682x; 1.0946x over previous
//
#include <hip/hip_runtime.h>
#include <cstdint>
#include <cstddef>

typedef float  f32x4  __attribute__((ext_vector_type(4)));
typedef short  bf16x8 __attribute__((ext_vector_type(8)));
typedef unsigned short u16x8 __attribute__((ext_vector_type(8)));

#define L_SEQ   8192
#define D_DIM   1024
#define N_COL   2048
#define N_PAIR  512
#define CHUNK_T 16
#define N_CHUNK 512

__device__ __forceinline__ unsigned short f2bf(float f) {
  unsigned int b = __float_as_uint(f);
  b += 0x7FFFu + ((b >> 16) & 1u);
  return (unsigned short)(b >> 16);
}
__device__ __forceinline__ float bf2f(unsigned short u) {
  return __uint_as_float((unsigned int)u << 16);
}
__device__ __forceinline__ void gload_lds16(const void* g, void* lds) {
  __builtin_amdgcn_global_load_lds(
      (const __attribute__((address_space(1))) void*)g,
      (__attribute__((address_space(3))) void*)lds, 16, 0, 0);
}
__device__ __forceinline__ float2 cmul(float2 a, float2 b) {
  return make_float2(a.x * b.x - a.y * b.y, a.x * b.y + a.y * b.x);
}
__device__ __forceinline__ float2 csqr(float2 a) {
  return make_float2(a.x * a.x - a.y * a.y, 2.f * a.x * a.y);
}
__device__ __forceinline__ void cfma2(const float4& lm, float2& h0, float2& h1,
                                      const float4& v) {
  float nr0 = fmaf(lm.x, h0.x, fmaf(-lm.y, h0.y, v.x));
  float ni0 = fmaf(lm.x, h0.y, fmaf(lm.y, h0.x, v.y));
  float nr1 = fmaf(lm.z, h1.x, fmaf(-lm.w, h1.y, v.z));
  float ni1 = fmaf(lm.z, h1.y, fmaf(lm.w, h1.x, v.w));
  h0.x = nr0; h0.y = ni0; h1.x = nr1; h1.y = ni1;
}

// ---------- K1: fused prep ----------
__global__ __launch_bounds__(256) void k_prep(
    const float* __restrict__ in, const float* __restrict__ Bre,
    const float* __restrict__ Bim, const float* __restrict__ gamma_log,
    const float* __restrict__ theta, const float* __restrict__ nu,
    unsigned short* __restrict__ A, unsigned short* __restrict__ W,
    float2* __restrict__ lam) {
  int b = blockIdx.x;
  if (b < 4096) {
    int i = b * 256 + threadIdx.x;
    const float4* p = (const float4*)in;
    float4 a = p[2 * i], c = p[2 * i + 1];
    u16x8 o;
    o[0] = f2bf(a.x); o[1] = f2bf(a.y); o[2] = f2bf(a.z); o[3] = f2bf(a.w);
    o[4] = f2bf(c.x); o[5] = f2bf(c.y); o[6] = f2bf(c.z); o[7] = f2bf(c.w);
    *(u16x8*)(A + (size_t)i * 8) = o;
  } else if (b < 5120) {
    int t = (b - 4096) * 256 + threadIdx.x;
    int row = t >> 7;
    int seg = t & 127;
    int k = row >> 1;
    const float* src = (row & 1) ? Bim : Bre;
    float g = expf(gamma_log[k]);
    const float4* p = (const float4*)(src + (size_t)k * D_DIM + seg * 8);
    float4 a = p[0], c = p[1];
    u16x8 o;
    o[0] = f2bf(a.x * g); o[1] = f2bf(a.y * g); o[2] = f2bf(a.z * g); o[3] = f2bf(a.w * g);
    o[4] = f2bf(c.x * g); o[5] = f2bf(c.y * g); o[6] = f2bf(c.z * g); o[7] = f2bf(c.w * g);
    *(u16x8*)(W + (size_t)row * D_DIM + seg * 8) = o;
  } else {
    int k = (b - 5120) * 256 + threadIdx.x;
    if (k < D_DIM) {
      float mod = expf(-expf(nu[k]));
      float ang = expf(theta[k]);
      lam[k] = make_float2(mod * cosf(ang), mod * sinf(ang));
    }
  }
}

// ---------- K2: 256x256x64 8-wave 4-phase/K-tile GEMM, counted vmcnt ----------
// Bu[8192][2048] = A[8192][1024] * W[2048][1024]^T
__global__ __launch_bounds__(512, 1) void k_gemm(const unsigned short* __restrict__ A,
                                                 const unsigned short* __restrict__ W,
                                                 float* __restrict__ Bu) {
  extern __shared__ char smem[];   // [A:2buf x 2half x 16KB][B: same] = 128 KiB

  const int tid = threadIdx.x;
  const int l = tid & 63, w = tid >> 6;
  const int wm = w >> 2, wn = w & 3;

  // XCD-chunked bijective swizzle (256 blocks, 8 XCDs, q=32)
  int orig = blockIdx.x;
  int wgid = (orig & 7) * 32 + (orig >> 3);
  const int mt = wgid >> 3, nt = wgid & 7;
  const size_t m0 = (size_t)mt * 256, n0 = (size_t)nt * 256;

  // staging addresses: thread stages 2x16B per half-tile (128 rows x 64 k)
  const int srow = tid >> 3;              // 0..63 ; +64 for second load
  const int scs  = tid & 7;
  const int cA   = scs ^ (srow & 7);      // pre-swizzled source chunk
  const size_t srcoff0 = (size_t)srow * 2048 + (size_t)cA * 16;
  const size_t srcoff1 = srcoff0 + 64 * 2048;
  const int dst0 = tid * 16, dst1 = 8192 + tid * 16;

#define STAGE(Mptr, Mbase, Msel, bb, hh, TT) do {                                   \
    const char* s_ = (const char*)(Mptr) +                                          \
        (((Mbase) + (size_t)(hh) * 128) * 2048 + (size_t)(TT) * 128);               \
    char* d_ = smem + (Msel) * 65536 + (bb) * 32768 + (hh) * 16384;                 \
    gload_lds16(s_ + srcoff0, d_ + dst0);                                           \
    gload_lds16(s_ + srcoff1, d_ + dst1);                                           \
  } while (0)

  // fragment read offsets
  int aroff[8], broff[4];
#pragma unroll
  for (int fr = 0; fr < 8; ++fr) {
    int lrow = fr * 32 + wm * 16 + (l & 15);
    aroff[fr] = (lrow >> 7) * 16384 + (lrow & 127) * 128;
  }
#pragma unroll
  for (int fn = 0; fn < 4; ++fn) {
    int lrow = fn * 64 + wn * 16 + (l & 15);
    broff[fn] = (lrow >> 7) * 16384 + (lrow & 127) * 128;
  }
  const int swk0 = (((l >> 4)) ^ (l & 7)) << 4;
  const int swk1 = ((4 + (l >> 4)) ^ (l & 7)) << 4;

  f32x4 acc[8][4];
#pragma unroll
  for (int m = 0; m < 8; ++m)
#pragma unroll
    for (int n = 0; n < 4; ++n) acc[m][n] = (f32x4){0.f, 0.f, 0.f, 0.f};

  bf16x8 af[4][2], bfr[4][2];

#define LGKMC0 asm volatile("s_waitcnt lgkmcnt(0)" ::: "memory")
#define VMCNT4 asm volatile("s_waitcnt vmcnt(4)" ::: "memory")
#define BAR()  do { asm volatile("" ::: "memory"); __builtin_amdgcn_s_barrier(); \
                    asm volatile("" ::: "memory"); } while (0)

  // prologue: stage B0(0), A1(0), A0(0), B1(0), B0(1), A1(1)
  STAGE(W, n0, 1, 0, 0, 0);
  STAGE(A, m0, 0, 0, 1, 0);
  STAGE(A, m0, 0, 0, 0, 0);
  STAGE(W, n0, 1, 0, 1, 0);
  STAGE(W, n0, 1, 1, 0, 1);
  STAGE(A, m0, 0, 1, 1, 1);
  VMCNT4;
  BAR();

  for (int kt = 0; kt < 16; ++kt) {
    const int buf = kt & 1;
    const int abase = buf * 32768;
    const int bbase = 65536 + buf * 32768;
    const int t1 = (kt + 1 < 16) ? kt + 1 : 15;   // source-tile clamp (dst parity fixed)
    const int t2 = (kt + 2 < 16) ? kt + 2 : 15;
    const int b1 = (kt + 1) & 1, b2 = kt & 1;

    // ---- phase 1: quadrant (qa=0, fn=0,1); read A-half0 + B-half0; stage A0(kt+1)
#pragma unroll
    for (int i = 0; i < 4; ++i) {
      af[i][0] = *(const bf16x8*)(smem + abase + aroff[i] + swk0);
      af[i][1] = *(const bf16x8*)(smem + abase + aroff[i] + swk1);
    }
#pragma unroll
    for (int fn = 0; fn < 2; ++fn) {
      bfr[fn][0] = *(const bf16x8*)(smem + bbase + broff[fn] + swk0);
      bfr[fn][1] = *(const bf16x8*)(smem + bbase + broff[fn] + swk1);
    }
    STAGE(A, m0, 0, b1, 0, t1);
    __builtin_amdgcn_s_setprio(1);
#pragma unroll
    for (int i = 0; i < 4; ++i)
#pragma unroll
      for (int fn = 0; fn < 2; ++fn) {
        acc[i][fn] = __builtin_amdgcn_mfma_f32_16x16x32_bf16(af[i][0], bfr[fn][0], acc[i][fn], 0, 0, 0);
        acc[i][fn] = __builtin_amdgcn_mfma_f32_16x16x32_bf16(af[i][1], bfr[fn][1], acc[i][fn], 0, 0, 0);
      }
    __builtin_amdgcn_s_setprio(0);
    LGKMC0;
    BAR();

    // ---- phase 2: quadrant (qa=0, fn=2,3); read B-half1; stage B1(kt+1)
#pragma unroll
    for (int fn = 2; fn < 4; ++fn) {
      bfr[fn][0] = *(const bf16x8*)(smem + bbase + broff[fn] + swk0);
      bfr[fn][1] = *(const bf16x8*)(smem + bbase + broff[fn] + swk1);
    }
    STAGE(W, n0, 1, b1, 1, t1);
    __builtin_amdgcn_s_setprio(1);
#pragma unroll
    for (int i = 0; i < 4; ++i)
#pragma unroll
      for (int fn = 2; fn < 4; ++fn) {
        acc[i][fn] = __builtin_amdgcn_mfma_f32_16x16x32_bf16(af[i][0], bfr[fn][0], acc[i][fn], 0, 0, 0);
        acc[i][fn] = __builtin_amdgcn_mfma_f32_16x16x32_bf16(af[i][1], bfr[fn][1], acc[i][fn], 0, 0, 0);
      }
    __builtin_amdgcn_s_setprio(0);
    LGKMC0;
    BAR();

    // ---- phase 3: quadrant (qa=1, fn=2,3); read A-half1; stage B0(kt+2)
#pragma unroll
    for (int i = 0; i < 4; ++i) {
      af[i][0] = *(const bf16x8*)(smem + abase + aroff[4 + i] + swk0);
      af[i][1] = *(const bf16x8*)(smem + abase + aroff[4 + i] + swk1);
    }
    STAGE(W, n0, 1, b2, 0, t2);
    __builtin_amdgcn_s_setprio(1);
#pragma unroll
    for (int i = 0; i < 4; ++i)
#pragma unroll
      for (int fn = 2; fn < 4; ++fn) {
        acc[4 + i][fn] = __builtin_amdgcn_mfma_f32_16x16x32_bf16(af[i][0], bfr[fn][0], acc[4 + i][fn], 0, 0, 0);
        acc[4 + i][fn] = __builtin_amdgcn_mfma_f32_16x16x32_bf16(af[i][1], bfr[fn][1], acc[4 + i][fn], 0, 0, 0);
      }
    __builtin_amdgcn_s_setprio(0);
    LGKMC0;
    BAR();

    // ---- phase 4: quadrant (qa=1, fn=0,1); no reads; stage A1(kt+2)
    STAGE(A, m0, 0, b2, 1, t2);
    __builtin_amdgcn_s_setprio(1);
#pragma unroll
    for (int i = 0; i < 4; ++i)
#pragma unroll
      for (int fn = 0; fn < 2; ++fn) {
        acc[4 + i][fn] = __builtin_amdgcn_mfma_f32_16x16x32_bf16(af[i][0], bfr[fn][0], acc[4 + i][fn], 0, 0, 0);
        acc[4 + i][fn] = __builtin_amdgcn_mfma_f32_16x16x32_bf16(af[i][1], bfr[fn][1], acc[4 + i][fn], 0, 0, 0);
      }
    __builtin_amdgcn_s_setprio(0);
    VMCNT4;
    BAR();
  }
#undef STAGE

  // epilogue
#pragma unroll
  for (int fr = 0; fr < 8; ++fr)
#pragma unroll
    for (int fn = 0; fn < 4; ++fn) {
      size_t col = n0 + fn * 64 + wn * 16 + (l & 15);
#pragma unroll
      for (int j = 0; j < 4; ++j) {
        size_t row = m0 + fr * 32 + wm * 16 + (l >> 4) * 4 + j;
        Bu[row * N_COL + col] = acc[fr][fn][j];
      }
    }
}

// ---------- K3: per-chunk local scan finals ----------
__global__ __launch_bounds__(256) void k_scan1(const float4* __restrict__ Bu4,
                                               const float4* __restrict__ lam4,
                                               float4* __restrict__ agg4) {
  int t = blockIdx.x * 256 + threadIdx.x;
  int c = t >> 9, j = t & 511;
  float4 lm = lam4[j];
  float2 h0 = {0.f, 0.f}, h1 = {0.f, 0.f};
  const float4* p = Bu4 + (size_t)c * CHUNK_T * N_PAIR + j;
#pragma unroll
  for (int s = 0; s < CHUNK_T; ++s) {
    float4 v = p[(size_t)s * N_PAIR];
    cfma2(lm, h0, h1, v);
  }
  agg4[(size_t)c * N_PAIR + j] = make_float4(h0.x, h0.y, h1.x, h1.y);
}

// ---------- K4: wave-parallel scan of chunk aggregates ----------
__global__ __launch_bounds__(256) void k_scan2(const float4* __restrict__ agg4,
                                               const float4* __restrict__ lam4,
                                               float4* __restrict__ carry4) {
  int wave = blockIdx.x * 4 + (threadIdx.x >> 6);
  int lane = threadIdx.x & 63;
  int j = wave;
  float4 lm = lam4[j];
  float2 lT0 = {lm.x, lm.y}, lT1 = {lm.z, lm.w};
#pragma unroll
  for (int i = 0; i < 4; ++i) { lT0 = csqr(lT0); lT1 = csqr(lT1); }

  float4 a[8];
  float2 T0 = {0.f, 0.f}, T1 = {0.f, 0.f};
  float4 lTv = make_float4(lT0.x, lT0.y, lT1.x, lT1.y);
#pragma unroll
  for (int i = 0; i < 8; ++i) {
    a[i] = agg4[(size_t)(lane * 8 + i) * N_PAIR + j];
    cfma2(lTv, T0, T1, a[i]);
  }

  float2 M0 = lT0, M1 = lT1;
#pragma unroll
  for (int i = 0; i < 3; ++i) { M0 = csqr(M0); M1 = csqr(M1); }
  float2 S0 = T0, S1 = T1;
#pragma unroll
  for (int d = 1; d < 64; d <<= 1) {
    float2 u0, u1;
    u0.x = __shfl_up(S0.x, d); u0.y = __shfl_up(S0.y, d);
    u1.x = __shfl_up(S1.x, d); u1.y = __shfl_up(S1.y, d);
    if (lane >= d) {
      float2 m0 = cmul(M0, u0), m1 = cmul(M1, u1);
      S0.x += m0.x; S0.y += m0.y; S1.x += m1.x; S1.y += m1.y;
    }
    M0 = csqr(M0); M1 = csqr(M1);
  }
  float2 P0, P1;
  P0.x = __shfl_up(S0.x, 1); P0.y = __shfl_up(S0.y, 1);
  P1.x = __shfl_up(S1.x, 1); P1.y = __shfl_up(S1.y, 1);
  if (lane == 0) { P0 = make_float2(0.f, 0.f); P1 = make_float2(0.f, 0.f); }

#pragma unroll
  for (int i = 0; i < 8; ++i) {
    carry4[(size_t)(lane * 8 + i) * N_PAIR + j] = make_float4(P0.x, P0.y, P1.x, P1.y);
    cfma2(lTv, P0, P1, a[i]);
  }
}

// ---------- K5: final rescan + output (reads bf16 inputs copy) ----------
__global__ __launch_bounds__(256) void k_scan3(const float4* __restrict__ Bu4,
                                               const float4* __restrict__ lam4,
                                               const float4* __restrict__ carry4,
                                               const ushort4* __restrict__ inA,
                                               float4* __restrict__ out4) {
  int t = blockIdx.x * 256 + threadIdx.x;
  int c = t >> 8, q = t & 255;
  float4 lm0 = lam4[2 * q], lm1 = lam4[2 * q + 1];
  float4 cv0 = carry4[(size_t)c * N_PAIR + 2 * q];
  float4 cv1 = carry4[(size_t)c * N_PAIR + 2 * q + 1];
  float2 h0 = {cv0.x, cv0.y}, h1 = {cv0.z, cv0.w};
  float2 h2 = {cv1.x, cv1.y}, h3 = {cv1.z, cv1.w};
#pragma unroll
  for (int s = 0; s < CHUNK_T; ++s) {
    size_t row = (size_t)c * CHUNK_T + s;
    float4 v0 = Bu4[row * N_PAIR + 2 * q];
    float4 v1 = Bu4[row * N_PAIR + 2 * q + 1];
    cfma2(lm0, h0, h1, v0);
    cfma2(lm1, h2, h3, v1);
    ushort4 iv = inA[row * 256 + q];
    out4[row * 256 + q] = make_float4(h0.x + bf2f(iv.x), h1.x + bf2f(iv.y),
                                      h2.x + bf2f(iv.z), h3.x + bf2f(iv.w));
  }
}

extern "C" void kernel_launch(void* const* d_in, const int* in_sizes, int n_in,
                              void* d_out, int out_size, void* d_ws, size_t ws_size,
                              hipStream_t stream) {
  (void)in_sizes; (void)n_in; (void)out_size; (void)ws_size;
  const float* inputs    = (const float*)d_in[0];
  const float* theta     = (const float*)d_in[1];
  const float* nu        = (const float*)d_in[2];
  const float* gamma_log = (const float*)d_in[3];
  const float* Bre       = (const float*)d_in[4];
  const float* Bim       = (const float*)d_in[5];

  char* ws = (char*)d_ws;
  float2*         lam   = (float2*)ws;
  unsigned short* A     = (unsigned short*)(ws + (1 << 16));
  unsigned short* W     = (unsigned short*)(ws + (1 << 16) + (16u << 20));
  float*          Bu    = (float*)(ws + (1 << 16) + (20u << 20));
  float4*         agg   = (float4*)(ws + (1 << 16) + (84u << 20));
  float4*         carry = (float4*)(ws + (1 << 16) + (88u << 20));

  static_assert(sizeof(float4) == 16, "");
  hipFuncSetAttribute((const void*)k_gemm,
                      hipFuncAttributeMaxDynamicSharedMemorySize, 131072);

  k_prep<<<5124, 256, 0, stream>>>(inputs, Bre, Bim, gamma_log, theta, nu, A, W, lam);
  k_gemm<<<256, 512, 131072, stream>>>(A, W, Bu);
  k_scan1<<<(N_CHUNK * N_PAIR) / 256, 256, 0, stream>>>((const float4*)Bu,
                                                        (const float4*)lam, agg);
  k_scan2<<<N_PAIR / 4, 256, 0, stream>>>(agg, (const float4*)lam, carry);
  k_scan3<<<(N_CHUNK * 256) / 256, 256, 0, stream>>>((const float4*)Bu,
                                                     (const float4*)lam, carry,
                                                     (const ushort4*)A,
                                                     (float4*)d_out);
}

// Round 4
// 69.587 us; speedup vs baseline: 1.5822x; 1.2476x over previous
//
#include <hip/hip_runtime.h>
#include <cstdint>
#include <cstddef>

typedef float  f32x4  __attribute__((ext_vector_type(4)));
typedef short  bf16x8 __attribute__((ext_vector_type(8)));
typedef unsigned short u16x8 __attribute__((ext_vector_type(8)));

#define L_SEQ   8192
#define D_DIM   1024
#define N_COL   2048
#define N_PAIR  512
#define CHUNK_T 16
#define N_CHUNK 512

__device__ __forceinline__ unsigned short f2bf(float f) {
  unsigned int b = __float_as_uint(f);
  b += 0x7FFFu + ((b >> 16) & 1u);
  return (unsigned short)(b >> 16);
}
__device__ __forceinline__ float bf2f(unsigned short u) {
  return __uint_as_float((unsigned int)u << 16);
}
__device__ __forceinline__ void gload_lds16(const void* g, void* lds) {
  __builtin_amdgcn_global_load_lds(
      (const __attribute__((address_space(1))) void*)g,
      (__attribute__((address_space(3))) void*)lds, 16, 0, 0);
}
__device__ __forceinline__ float2 cmul(float2 a, float2 b) {
  return make_float2(a.x * b.x - a.y * b.y, a.x * b.y + a.y * b.x);
}
__device__ __forceinline__ float2 csqr(float2 a) {
  return make_float2(a.x * a.x - a.y * a.y, 2.f * a.x * a.y);
}
__device__ __forceinline__ void cfma2(const float4& lm, float2& h0, float2& h1,
                                      const float4& v) {
  float nr0 = fmaf(lm.x, h0.x, fmaf(-lm.y, h0.y, v.x));
  float ni0 = fmaf(lm.x, h0.y, fmaf(lm.y, h0.x, v.y));
  float nr1 = fmaf(lm.z, h1.x, fmaf(-lm.w, h1.y, v.z));
  float ni1 = fmaf(lm.z, h1.y, fmaf(lm.w, h1.x, v.w));
  h0.x = nr0; h0.y = ni0; h1.x = nr1; h1.y = ni1;
}

// ---------- K1: fused prep ----------
__global__ __launch_bounds__(256) void k_prep(
    const float* __restrict__ in, const float* __restrict__ Bre,
    const float* __restrict__ Bim, const float* __restrict__ gamma_log,
    const float* __restrict__ theta, const float* __restrict__ nu,
    unsigned short* __restrict__ A, unsigned short* __restrict__ W,
    float2* __restrict__ lam) {
  int b = blockIdx.x;
  if (b < 4096) {
    int i = b * 256 + threadIdx.x;
    const float4* p = (const float4*)in;
    float4 a = p[2 * i], c = p[2 * i + 1];
    u16x8 o;
    o[0] = f2bf(a.x); o[1] = f2bf(a.y); o[2] = f2bf(a.z); o[3] = f2bf(a.w);
    o[4] = f2bf(c.x); o[5] = f2bf(c.y); o[6] = f2bf(c.z); o[7] = f2bf(c.w);
    *(u16x8*)(A + (size_t)i * 8) = o;
  } else if (b < 5120) {
    int t = (b - 4096) * 256 + threadIdx.x;
    int row = t >> 7;
    int seg = t & 127;
    int k = row >> 1;
    const float* src = (row & 1) ? Bim : Bre;
    float g = expf(gamma_log[k]);
    const float4* p = (const float4*)(src + (size_t)k * D_DIM + seg * 8);
    float4 a = p[0], c = p[1];
    u16x8 o;
    o[0] = f2bf(a.x * g); o[1] = f2bf(a.y * g); o[2] = f2bf(a.z * g); o[3] = f2bf(a.w * g);
    o[4] = f2bf(c.x * g); o[5] = f2bf(c.y * g); o[6] = f2bf(c.z * g); o[7] = f2bf(c.w * g);
    *(u16x8*)(W + (size_t)row * D_DIM + seg * 8) = o;
  } else {
    int k = (b - 5120) * 256 + threadIdx.x;
    if (k < D_DIM) {
      float mod = expf(-expf(nu[k]));
      float ang = expf(theta[k]);
      lam[k] = make_float2(mod * cosf(ang), mod * sinf(ang));
    }
  }
}

// ---------- K2: 256x256x64 GEMM + fused chunk-aggregate scan, bf16 Bu out ----------
__global__ __launch_bounds__(512, 1) void k_gemm(const unsigned short* __restrict__ A,
                                                 const unsigned short* __restrict__ W,
                                                 unsigned short* __restrict__ Bu16,
                                                 float2* __restrict__ agg2,
                                                 const float2* __restrict__ lam) {
  extern __shared__ char smem[];   // main loop: [A:2x2x16KB][B: same]; epilogue: 256x512B tile

  const int tid = threadIdx.x;
  const int l = tid & 63, w = tid >> 6;
  const int wm = w >> 2, wn = w & 3;

  int orig = blockIdx.x;
  int wgid = (orig & 7) * 32 + (orig >> 3);       // XCD-chunked bijective swizzle
  const int mt = wgid >> 3, nt = wgid & 7;
  const size_t m0 = (size_t)mt * 256, n0 = (size_t)nt * 256;

  const int srow = tid >> 3;
  const int scs  = tid & 7;
  const int cA   = scs ^ (srow & 7);
  const size_t srcoff0 = (size_t)srow * 2048 + (size_t)cA * 16;
  const size_t srcoff1 = srcoff0 + 64 * 2048;
  const int dst0 = tid * 16, dst1 = 8192 + tid * 16;

#define STAGE(Mptr, Mbase, Msel, bb, hh, TT) do {                                   \
    const char* s_ = (const char*)(Mptr) +                                          \
        (((Mbase) + (size_t)(hh) * 128) * 2048 + (size_t)(TT) * 128);               \
    char* d_ = smem + (Msel) * 65536 + (bb) * 32768 + (hh) * 16384;                 \
    gload_lds16(s_ + srcoff0, d_ + dst0);                                           \
    gload_lds16(s_ + srcoff1, d_ + dst1);                                           \
  } while (0)

  int aroff[8], broff[4];
#pragma unroll
  for (int fr = 0; fr < 8; ++fr) {
    int lrow = fr * 32 + wm * 16 + (l & 15);
    aroff[fr] = (lrow >> 7) * 16384 + (lrow & 127) * 128;
  }
#pragma unroll
  for (int fn = 0; fn < 4; ++fn) {
    int lrow = fn * 64 + wn * 16 + (l & 15);
    broff[fn] = (lrow >> 7) * 16384 + (lrow & 127) * 128;
  }
  const int swk0 = (((l >> 4)) ^ (l & 7)) << 4;
  const int swk1 = ((4 + (l >> 4)) ^ (l & 7)) << 4;

  f32x4 acc[8][4];
#pragma unroll
  for (int m = 0; m < 8; ++m)
#pragma unroll
    for (int n = 0; n < 4; ++n) acc[m][n] = (f32x4){0.f, 0.f, 0.f, 0.f};

  bf16x8 af[4][2], bfr[4][2];

#define LGKMC0 asm volatile("s_waitcnt lgkmcnt(0)" ::: "memory")
#define VMCNT4 asm volatile("s_waitcnt vmcnt(4)" ::: "memory")
#define VMCNT0 asm volatile("s_waitcnt vmcnt(0)" ::: "memory")
#define BAR()  do { asm volatile("" ::: "memory"); __builtin_amdgcn_s_barrier(); \
                    asm volatile("" ::: "memory"); } while (0)

  // prologue
  STAGE(W, n0, 1, 0, 0, 0);
  STAGE(A, m0, 0, 0, 1, 0);
  STAGE(A, m0, 0, 0, 0, 0);
  STAGE(W, n0, 1, 0, 1, 0);
  STAGE(W, n0, 1, 1, 0, 1);
  STAGE(A, m0, 0, 1, 1, 1);
  VMCNT4;
  BAR();

  for (int kt = 0; kt < 16; ++kt) {
    const int buf = kt & 1;
    const int abase = buf * 32768;
    const int bbase = 65536 + buf * 32768;
    const int b1 = (kt + 1) & 1, b2 = kt & 1;
    const bool s1 = (kt + 1 < 16), s2 = (kt + 2 < 16);

    // phase 1: read A-half0 + B-half0; stage A0(kt+1); MFMA quad (0,fn01)
#pragma unroll
    for (int i = 0; i < 4; ++i) {
      af[i][0] = *(const bf16x8*)(smem + abase + aroff[i] + swk0);
      af[i][1] = *(const bf16x8*)(smem + abase + aroff[i] + swk1);
    }
#pragma unroll
    for (int fn = 0; fn < 2; ++fn) {
      bfr[fn][0] = *(const bf16x8*)(smem + bbase + broff[fn] + swk0);
      bfr[fn][1] = *(const bf16x8*)(smem + bbase + broff[fn] + swk1);
    }
    if (s1) STAGE(A, m0, 0, b1, 0, kt + 1);
    __builtin_amdgcn_s_setprio(1);
#pragma unroll
    for (int i = 0; i < 4; ++i)
#pragma unroll
      for (int fn = 0; fn < 2; ++fn) {
        acc[i][fn] = __builtin_amdgcn_mfma_f32_16x16x32_bf16(af[i][0], bfr[fn][0], acc[i][fn], 0, 0, 0);
        acc[i][fn] = __builtin_amdgcn_mfma_f32_16x16x32_bf16(af[i][1], bfr[fn][1], acc[i][fn], 0, 0, 0);
      }
    __builtin_amdgcn_s_setprio(0);
    LGKMC0;
    BAR();

    // phase 2: read B-half1; stage B1(kt+1); MFMA quad (0,fn23)
#pragma unroll
    for (int fn = 2; fn < 4; ++fn) {
      bfr[fn][0] = *(const bf16x8*)(smem + bbase + broff[fn] + swk0);
      bfr[fn][1] = *(const bf16x8*)(smem + bbase + broff[fn] + swk1);
    }
    if (s1) STAGE(W, n0, 1, b1, 1, kt + 1);
    __builtin_amdgcn_s_setprio(1);
#pragma unroll
    for (int i = 0; i < 4; ++i)
#pragma unroll
      for (int fn = 2; fn < 4; ++fn) {
        acc[i][fn] = __builtin_amdgcn_mfma_f32_16x16x32_bf16(af[i][0], bfr[fn][0], acc[i][fn], 0, 0, 0);
        acc[i][fn] = __builtin_amdgcn_mfma_f32_16x16x32_bf16(af[i][1], bfr[fn][1], acc[i][fn], 0, 0, 0);
      }
    __builtin_amdgcn_s_setprio(0);
    LGKMC0;
    BAR();

    // phase 3: read A-half1; stage B0(kt+2); MFMA quad (1,fn23)
#pragma unroll
    for (int i = 0; i < 4; ++i) {
      af[i][0] = *(const bf16x8*)(smem + abase + aroff[4 + i] + swk0);
      af[i][1] = *(const bf16x8*)(smem + abase + aroff[4 + i] + swk1);
    }
    if (s2) STAGE(W, n0, 1, b2, 0, kt + 2);
    __builtin_amdgcn_s_setprio(1);
#pragma unroll
    for (int i = 0; i < 4; ++i)
#pragma unroll
      for (int fn = 2; fn < 4; ++fn) {
        acc[4 + i][fn] = __builtin_amdgcn_mfma_f32_16x16x32_bf16(af[i][0], bfr[fn][0], acc[4 + i][fn], 0, 0, 0);
        acc[4 + i][fn] = __builtin_amdgcn_mfma_f32_16x16x32_bf16(af[i][1], bfr[fn][1], acc[4 + i][fn], 0, 0, 0);
      }
    __builtin_amdgcn_s_setprio(0);
    LGKMC0;
    BAR();

    // phase 4: stage A1(kt+2); MFMA quad (1,fn01)
    if (s2) STAGE(A, m0, 0, b2, 1, kt + 2);
    __builtin_amdgcn_s_setprio(1);
#pragma unroll
    for (int i = 0; i < 4; ++i)
#pragma unroll
      for (int fn = 0; fn < 2; ++fn) {
        acc[4 + i][fn] = __builtin_amdgcn_mfma_f32_16x16x32_bf16(af[i][0], bfr[fn][0], acc[4 + i][fn], 0, 0, 0);
        acc[4 + i][fn] = __builtin_amdgcn_mfma_f32_16x16x32_bf16(af[i][1], bfr[fn][1], acc[4 + i][fn], 0, 0, 0);
      }
    __builtin_amdgcn_s_setprio(0);
    if (kt < 14) VMCNT4; else VMCNT0;   // kt=14: drain tile-15 fully; kt=15: nothing outstanding
    BAR();
  }
#undef STAGE

  // ---- epilogue: acc -> LDS bf16 [256 rows][512 B], 16B-chunk XOR swizzle by row&7
#pragma unroll
  for (int fr = 0; fr < 8; ++fr)
#pragma unroll
    for (int fn = 0; fn < 4; ++fn) {
      int col = fn * 64 + wn * 16 + (l & 15);
#pragma unroll
      for (int j = 0; j < 4; ++j) {
        int row = fr * 32 + wm * 16 + (l >> 4) * 4 + j;
        int byte = row * 512 + ((col * 2) ^ ((row & 7) << 4));
        *(unsigned short*)(smem + byte) = f2bf(acc[fr][fn][j]);
      }
    }
  __syncthreads();

  // coalesced bf16 Bu write: 2 rows x 512B per wave-instruction
  {
    unsigned short* gbase = Bu16 + m0 * N_COL + n0;
#pragma unroll
    for (int pass = 0; pass < 16; ++pass) {
      int row = pass * 16 + (tid >> 5);
      int c = tid & 31;
      int byte = row * 512 + ((c * 16) ^ ((row & 7) << 4));
      f32x4 v = *(const f32x4*)(smem + byte);
      *(f32x4*)(gbase + (size_t)row * N_COL + c * 8) = v;
    }
  }

  // fused chunk-aggregate scan: 16 chunks x 128 channels from LDS
#pragma unroll
  for (int i = 0; i < 4; ++i) {
    int q = i * 512 + tid;
    int c = q >> 7, ch = q & 127;
    float2 lmv = lam[(n0 >> 1) + ch];
    float2 h = {0.f, 0.f};
#pragma unroll
    for (int s = 0; s < 16; ++s) {
      int row = c * 16 + s;
      int byte = row * 512 + ((ch * 4) ^ ((row & 7) << 4));
      unsigned int pr = *(const unsigned int*)(smem + byte);
      float br = bf2f((unsigned short)(pr & 0xFFFFu));
      float bi = bf2f((unsigned short)(pr >> 16));
      float nr = fmaf(lmv.x, h.x, fmaf(-lmv.y, h.y, br));
      float ni = fmaf(lmv.x, h.y, fmaf(lmv.y, h.x, bi));
      h.x = nr; h.y = ni;
    }
    agg2[(size_t)(mt * 16 + c) * 1024 + (n0 >> 1) + ch] = h;
  }
}

// ---------- K4: wave-parallel scan of chunk aggregates ----------
__global__ __launch_bounds__(256) void k_scan2(const float4* __restrict__ agg4,
                                               const float4* __restrict__ lam4,
                                               float4* __restrict__ carry4) {
  int wave = blockIdx.x * 4 + (threadIdx.x >> 6);
  int lane = threadIdx.x & 63;
  int j = wave;
  float4 lm = lam4[j];
  float2 lT0 = {lm.x, lm.y}, lT1 = {lm.z, lm.w};
#pragma unroll
  for (int i = 0; i < 4; ++i) { lT0 = csqr(lT0); lT1 = csqr(lT1); }

  float4 a[8];
  float2 T0 = {0.f, 0.f}, T1 = {0.f, 0.f};
  float4 lTv = make_float4(lT0.x, lT0.y, lT1.x, lT1.y);
#pragma unroll
  for (int i = 0; i < 8; ++i) {
    a[i] = agg4[(size_t)(lane * 8 + i) * N_PAIR + j];
    cfma2(lTv, T0, T1, a[i]);
  }

  float2 M0 = lT0, M1 = lT1;
#pragma unroll
  for (int i = 0; i < 3; ++i) { M0 = csqr(M0); M1 = csqr(M1); }
  float2 S0 = T0, S1 = T1;
#pragma unroll
  for (int d = 1; d < 64; d <<= 1) {
    float2 u0, u1;
    u0.x = __shfl_up(S0.x, d); u0.y = __shfl_up(S0.y, d);
    u1.x = __shfl_up(S1.x, d); u1.y = __shfl_up(S1.y, d);
    if (lane >= d) {
      float2 m0 = cmul(M0, u0), m1 = cmul(M1, u1);
      S0.x += m0.x; S0.y += m0.y; S1.x += m1.x; S1.y += m1.y;
    }
    M0 = csqr(M0); M1 = csqr(M1);
  }
  float2 P0, P1;
  P0.x = __shfl_up(S0.x, 1); P0.y = __shfl_up(S0.y, 1);
  P1.x = __shfl_up(S1.x, 1); P1.y = __shfl_up(S1.y, 1);
  if (lane == 0) { P0 = make_float2(0.f, 0.f); P1 = make_float2(0.f, 0.f); }

#pragma unroll
  for (int i = 0; i < 8; ++i) {
    carry4[(size_t)(lane * 8 + i) * N_PAIR + j] = make_float4(P0.x, P0.y, P1.x, P1.y);
    cfma2(lTv, P0, P1, a[i]);
  }
}

// ---------- K5: final rescan + output (bf16 Bu, bf16 inputs) ----------
__global__ __launch_bounds__(256) void k_scan3(const u16x8* __restrict__ Bu8,
                                               const float4* __restrict__ lam4,
                                               const float4* __restrict__ carry4,
                                               const ushort4* __restrict__ inA,
                                               float4* __restrict__ out4) {
  int t = blockIdx.x * 256 + threadIdx.x;
  int c = t >> 8, q = t & 255;
  float4 lm0 = lam4[2 * q], lm1 = lam4[2 * q + 1];
  float4 cv0 = carry4[(size_t)c * N_PAIR + 2 * q];
  float4 cv1 = carry4[(size_t)c * N_PAIR + 2 * q + 1];
  float2 h0 = {cv0.x, cv0.y}, h1 = {cv0.z, cv0.w};
  float2 h2 = {cv1.x, cv1.y}, h3 = {cv1.z, cv1.w};
#pragma unroll
  for (int s = 0; s < CHUNK_T; ++s) {
    size_t row = (size_t)c * CHUNK_T + s;
    u16x8 b = Bu8[row * 256 + q];
    float4 v0 = make_float4(bf2f(b[0]), bf2f(b[1]), bf2f(b[2]), bf2f(b[3]));
    float4 v1 = make_float4(bf2f(b[4]), bf2f(b[5]), bf2f(b[6]), bf2f(b[7]));
    cfma2(lm0, h0, h1, v0);
    cfma2(lm1, h2, h3, v1);
    ushort4 iv = inA[row * 256 + q];
    out4[row * 256 + q] = make_float4(h0.x + bf2f(iv.x), h1.x + bf2f(iv.y),
                                      h2.x + bf2f(iv.z), h3.x + bf2f(iv.w));
  }
}

extern "C" void kernel_launch(void* const* d_in, const int* in_sizes, int n_in,
                              void* d_out, int out_size, void* d_ws, size_t ws_size,
                              hipStream_t stream) {
  (void)in_sizes; (void)n_in; (void)out_size; (void)ws_size;
  const float* inputs    = (const float*)d_in[0];
  const float* theta     = (const float*)d_in[1];
  const float* nu        = (const float*)d_in[2];
  const float* gamma_log = (const float*)d_in[3];
  const float* Bre       = (const float*)d_in[4];
  const float* Bim       = (const float*)d_in[5];

  char* ws = (char*)d_ws;
  float2*         lam   = (float2*)ws;                                     // 8 KB
  unsigned short* A     = (unsigned short*)(ws + (1 << 16));               // 16 MB
  unsigned short* W     = (unsigned short*)(ws + (1 << 16) + (16u << 20)); // 4 MB
  unsigned short* Bu16  = (unsigned short*)(ws + (1 << 16) + (20u << 20)); // 32 MB
  float2*         agg   = (float2*)(ws + (1 << 16) + (52u << 20));         // 4 MB
  float4*         carry = (float4*)(ws + (1 << 16) + (56u << 20));         // 4 MB

  hipFuncSetAttribute((const void*)k_gemm,
                      hipFuncAttributeMaxDynamicSharedMemorySize, 131072);

  k_prep<<<5124, 256, 0, stream>>>(inputs, Bre, Bim, gamma_log, theta, nu, A, W, lam);
  k_gemm<<<256, 512, 131072, stream>>>(A, W, Bu16, agg, (const float2*)lam);
  k_scan2<<<N_PAIR / 4, 256, 0, stream>>>((const float4*)agg, (const float4*)lam, carry);
  k_scan3<<<(N_CHUNK * 256) / 256, 256, 0, stream>>>((const u16x8*)Bu16,
                                                     (const float4*)lam, carry,
                                                     (const ushort4*)A,
                                                     (float4*)d_out);
}